// Round 6
// baseline (359.169 us; speedup 1.0000x reference)
//
#include <hip/hip_runtime.h>
#include <hip/hip_bf16.h>

#define B_SZ   1024
#define HIDN   256
#define NSTAGE 6
#define NPTS   36
#define HGT    20
#define WID    20
#define HW     400
#define MB     4
#define NTHR   1024

// f32 -> bf16 round-to-nearest-even
static __device__ __forceinline__ unsigned int f2bf(float x) {
    unsigned int u = __float_as_uint(x);
    u += 0x7FFFu + ((u >> 16) & 1u);
    return u >> 16;
}
// bf16 bits -> f32 (exact)
static __device__ __forceinline__ float bf2f(unsigned short h) {
    return __uint_as_float((unsigned int)h << 16);
}

// ---------------------------------------------------------------------------
// Prepass v5: fmp[b][hw][c] = bf16(fm[b][c][hw] + pos[b][c][hw]).
// Tile: W hw x 128 c, bf16 in LDS (row stride 130 ushort = 65 words, ODD ->
// write-phase column gather banks 65*u = u mod 32: permutation, conflict-free).
// 512 threads, 33.3 KB LDS -> 4 blocks/CU = 32 waves/CU (100% occupancy).
// Read phase: 32 lanes x float4 = 512B contiguous per channel row chunk;
//   16 independent global loads in flight per thread.
// Write phase: thread u handles channels {u,u+32,u+64,u+96}; 2B stores,
//   64B contiguous per 32-lane phase (writes are only 205 MB total).
// W=128 main tiles (x3), W=16 tail (x1).
// ---------------------------------------------------------------------------
template <int W>
__global__ __launch_bounds__(512) void prepass_kernel(
    const float* __restrict__ fm, const float* __restrict__ pos,
    unsigned short* __restrict__ fmp, int hbase)
{
    const int b  = blockIdx.z;
    const int c0 = blockIdx.y * 128;
    const int h0 = hbase + blockIdx.x * 128;
    __shared__ unsigned short tile[128 * 130];   // 33,280 B
    const int t = threadIdx.x;

    // ---- read + convert phase ----
    const int f  = t & 31;                  // float4 index along hw
    const int cr = t >> 5;                  // 0..15
    if (4 * f < W) {
        #pragma unroll
        for (int cp = 0; cp < 8; ++cp) {
            const int cl = cp * 16 + cr;    // local channel 0..127
            const size_t ga = ((size_t)b * HIDN + (c0 + cl)) * HW + h0 + 4 * f;
            const float4 a = *(const float4*)(fm  + ga);
            const float4 p = *(const float4*)(pos + ga);
            uint2 pk;
            pk.x = f2bf(a.x + p.x) | (f2bf(a.y + p.y) << 16);
            pk.y = f2bf(a.z + p.z) | (f2bf(a.w + p.w) << 16);
            *(uint2*)&tile[cl * 130 + 4 * f] = pk;
        }
    }
    __syncthreads();

    // ---- transpose write phase ----
    const int u = t & 31;                   // channel low index 0..31
    const int r = t >> 5;                   // hw row within 16-row group
    #pragma unroll
    for (int wp = 0; wp < W / 16; ++wp) {
        const int hw = wp * 16 + r;
        const unsigned short v0 = tile[(u +  0) * 130 + hw];
        const unsigned short v1 = tile[(u + 32) * 130 + hw];
        const unsigned short v2 = tile[(u + 64) * 130 + hw];
        const unsigned short v3 = tile[(u + 96) * 130 + hw];
        unsigned short* orow = fmp + ((size_t)b * HW + h0 + hw) * HIDN + c0;
        orow[u +  0] = v0;
        orow[u + 32] = v1;
        orow[u + 64] = v2;
        orow[u + 96] = v3;
    }
}

// ---------------------------------------------------------------------------
// GEMM for 4 batch elements, no arrays (anti-spill), kp-split coalesced W.
// Thread layout: kp = t&7, og = t>>3 (0..127). O<=128 per pass.
// ACT: 0=none, 1=relu, 2=sigmoid.
// ---------------------------------------------------------------------------
template <int K, int O, int ACT>
__device__ __forceinline__ void gemm_v3(
    const float* __restrict__ W, const float* __restrict__ bias,
    const float* __restrict__ i0, const float* __restrict__ i1,
    const float* __restrict__ i2, const float* __restrict__ i3,
    float* __restrict__ o0, float* __restrict__ o1,
    float* __restrict__ o2, float* __restrict__ o3,
    int kp, int og)
{
    const float4* p0 = (const float4*)i0;
    const float4* p1 = (const float4*)i1;
    const float4* p2 = (const float4*)i2;
    const float4* p3 = (const float4*)i3;
    #pragma unroll
    for (int pass = 0; pass < (O + 127) / 128; ++pass) {
        const int o = pass * 128 + og;
        float a0 = 0.f, a1 = 0.f, a2 = 0.f, a3 = 0.f;
        if (o < O) {
            const float4* wr = (const float4*)(W + (size_t)o * K);
            #pragma unroll 4
            for (int jj = 0; jj < K / 32; ++jj) {
                const int j = kp + 8 * jj;
                const float4 w  = wr[j];
                const float4 v0 = p0[j];
                const float4 v1 = p1[j];
                const float4 v2 = p2[j];
                const float4 v3 = p3[j];
                a0 += w.x * v0.x + w.y * v0.y + w.z * v0.z + w.w * v0.w;
                a1 += w.x * v1.x + w.y * v1.y + w.z * v1.z + w.w * v1.w;
                a2 += w.x * v2.x + w.y * v2.y + w.z * v2.z + w.w * v2.w;
                a3 += w.x * v3.x + w.y * v3.y + w.z * v3.z + w.w * v3.w;
            }
        }
        a0 += __shfl_xor(a0, 1); a0 += __shfl_xor(a0, 2); a0 += __shfl_xor(a0, 4);
        a1 += __shfl_xor(a1, 1); a1 += __shfl_xor(a1, 2); a1 += __shfl_xor(a1, 4);
        a2 += __shfl_xor(a2, 1); a2 += __shfl_xor(a2, 2); a2 += __shfl_xor(a2, 4);
        a3 += __shfl_xor(a3, 1); a3 += __shfl_xor(a3, 2); a3 += __shfl_xor(a3, 4);
        if (kp == 0 && o < O) {
            const float bz = bias[o];
            float r0 = a0 + bz, r1 = a1 + bz, r2 = a2 + bz, r3 = a3 + bz;
            if (ACT == 1) {
                r0 = fmaxf(r0, 0.f); r1 = fmaxf(r1, 0.f);
                r2 = fmaxf(r2, 0.f); r3 = fmaxf(r3, 0.f);
            }
            if (ACT == 2) {
                r0 = 1.f / (1.f + expf(-r0)); r1 = 1.f / (1.f + expf(-r1));
                r2 = 1.f / (1.f + expf(-r2)); r3 = 1.f / (1.f + expf(-r3));
            }
            o0[o] = r0; o1[o] = r1; o2[o] = r2; o3[o] = r3;
        }
    }
}

// ---------------------------------------------------------------------------
// Fused main kernel v4: 1 block = 4 batch elements, 1024 threads, 256 blocks.
// Gathers from bf16 fmp (coalesced 128B/wave ushort loads).
// ---------------------------------------------------------------------------
__global__ __launch_bounds__(NTHR) void mdetr4_kernel(
    const float* __restrict__ q_in,  const float* __restrict__ refpt,
    const unsigned short* __restrict__ fmp,
    const float* __restrict__ offW,  const float* __restrict__ offB,
    const float* __restrict__ uW1,   const float* __restrict__ uB1,
    const float* __restrict__ uW2,   const float* __restrict__ uB2,
    const float* __restrict__ bW1,   const float* __restrict__ bb1,
    const float* __restrict__ bW2,   const float* __restrict__ bb2,
    const float* __restrict__ bW3,   const float* __restrict__ bb3,
    float* __restrict__ out)
{
    const int b0 = blockIdx.x * MB;
    const int t  = threadIdx.x;
    const int kp = t & 7;
    const int og = t >> 3;

    __shared__ __attribute__((aligned(16))) float cat_s[MB][2 * HIDN]; // [fused|q]
    __shared__ __attribute__((aligned(16))) float hdd_s[MB][HIDN];
    __shared__ __attribute__((aligned(16))) float xy_s[MB][80];
    __shared__ __attribute__((aligned(16))) float wgt_s[MB][144];
    __shared__ __attribute__((aligned(16))) int   off_s[MB][144];

    {   // initial q
        const int m = t >> 8, c = t & 255;
        cat_s[m][HIDN + c] = q_in[(size_t)(b0 + m) * HIDN + c];
    }

    for (int s = 0; s < NSTAGE; ++s) {
        __syncthreads();
        // ---- offset generator ----
        gemm_v3<HIDN, NPTS * 2, 0>(
            offW + (size_t)s * NPTS * 2 * HIDN, offB + s * NPTS * 2,
            cat_s[0] + HIDN, cat_s[1] + HIDN, cat_s[2] + HIDN, cat_s[3] + HIDN,
            xy_s[0], xy_s[1], xy_s[2], xy_s[3], kp, og);
        __syncthreads();
        // ---- tap prep ----
        if (t < MB * NPTS) {
            const int m = t / NPTS, p = t % NPTS;
            const int bm = b0 + m;
            float px = xy_s[m][2 * p + 0] + refpt[2 * bm + 0];
            float py = xy_s[m][2 * p + 1] + refpt[2 * bm + 1];
            float x = fminf(fmaxf(px * (float)WID - 0.5f, 0.f), (float)(WID - 1));
            float y = fminf(fmaxf(py * (float)HGT - 0.5f, 0.f), (float)(HGT - 1));
            float x0f = floorf(x), y0f = floorf(y);
            float wx = x - x0f,   wy = y - y0f;
            int x0 = (int)x0f, y0 = (int)y0f;
            int x1 = min(x0 + 1, WID - 1), y1 = min(y0 + 1, HGT - 1);
            const float inv = 1.f / (float)NPTS;
            wgt_s[m][4 * p + 0] = (1.f - wx) * (1.f - wy) * inv;
            wgt_s[m][4 * p + 1] = wx * (1.f - wy) * inv;
            wgt_s[m][4 * p + 2] = (1.f - wx) * wy * inv;
            wgt_s[m][4 * p + 3] = wx * wy * inv;
            off_s[m][4 * p + 0] = (y0 * WID + x0) * HIDN;
            off_s[m][4 * p + 1] = (y0 * WID + x1) * HIDN;
            off_s[m][4 * p + 2] = (y1 * WID + x0) * HIDN;
            off_s[m][4 * p + 3] = (y1 * WID + x1) * HIDN;
        }
        __syncthreads();
        // ---- gather + pooled mean -> fused ----
        {
            const int m = t >> 8, c = t & 255;
            const unsigned short* base = fmp + (size_t)(b0 + m) * HW * HIDN + c;
            float acc = 0.f;
            #pragma unroll 6
            for (int p = 0; p < NPTS; ++p) {
                const int4   o4 = ((const int4*)off_s[m])[p];
                const float4 w4 = ((const float4*)wgt_s[m])[p];
                acc += w4.x * bf2f(base[o4.x]) + w4.y * bf2f(base[o4.y])
                     + w4.z * bf2f(base[o4.z]) + w4.w * bf2f(base[o4.w]);
            }
            cat_s[m][c] = acc;
        }
        __syncthreads();
        // ---- MLP1 ----
        gemm_v3<2 * HIDN, HIDN, 1>(
            uW1 + (size_t)s * HIDN * 2 * HIDN, uB1 + s * HIDN,
            cat_s[0], cat_s[1], cat_s[2], cat_s[3],
            hdd_s[0], hdd_s[1], hdd_s[2], hdd_s[3], kp, og);
        __syncthreads();
        // ---- MLP2 ----
        gemm_v3<HIDN, HIDN, 0>(
            uW2 + (size_t)s * HIDN * HIDN, uB2 + s * HIDN,
            hdd_s[0], hdd_s[1], hdd_s[2], hdd_s[3],
            cat_s[0] + HIDN, cat_s[1] + HIDN, cat_s[2] + HIDN, cat_s[3] + HIDN,
            kp, og);
    }
    __syncthreads();
    // ---- bbox head ----
    gemm_v3<HIDN, HIDN, 1>(bW1, bb1,
        cat_s[0] + HIDN, cat_s[1] + HIDN, cat_s[2] + HIDN, cat_s[3] + HIDN,
        hdd_s[0], hdd_s[1], hdd_s[2], hdd_s[3], kp, og);
    __syncthreads();
    gemm_v3<HIDN, HIDN, 1>(bW2, bb2,
        hdd_s[0], hdd_s[1], hdd_s[2], hdd_s[3],
        cat_s[0], cat_s[1], cat_s[2], cat_s[3], kp, og);
    __syncthreads();
    gemm_v3<HIDN, 4, 2>(bW3, bb3,
        cat_s[0], cat_s[1], cat_s[2], cat_s[3],
        out + (size_t)(b0 + 0) * 4, out + (size_t)(b0 + 1) * 4,
        out + (size_t)(b0 + 2) * 4, out + (size_t)(b0 + 3) * 4, kp, og);
}

// ---------------------------------------------------------------------------
// Fallback (no workspace): 1 block = 1 batch element, direct strided gather.
// ---------------------------------------------------------------------------
__global__ __launch_bounds__(256) void mdetr_direct_kernel(
    const float* __restrict__ q_in,  const float* __restrict__ refpt,
    const float* __restrict__ fm,    const float* __restrict__ pos,
    const float* __restrict__ offW,  const float* __restrict__ offB,
    const float* __restrict__ uW1,   const float* __restrict__ uB1,
    const float* __restrict__ uW2,   const float* __restrict__ uB2,
    const float* __restrict__ bW1,   const float* __restrict__ bb1,
    const float* __restrict__ bW2,   const float* __restrict__ bb2,
    const float* __restrict__ bW3,   const float* __restrict__ bb3,
    float* __restrict__ out)
{
    const int b = blockIdx.x;
    const int t = threadIdx.x;
    __shared__ __attribute__((aligned(16))) float q_s[HIDN];
    __shared__ __attribute__((aligned(16))) float fused_s[HIDN];
    __shared__ __attribute__((aligned(16))) float hdd_s[HIDN];
    __shared__ float xy_s[NPTS * 2];
    __shared__ int   off_s[NPTS * 4];
    __shared__ float w_s[NPTS * 4];

    q_s[t] = q_in[(size_t)b * HIDN + t];
    const float rpx = refpt[2 * b + 0];
    const float rpy = refpt[2 * b + 1];

    for (int s = 0; s < NSTAGE; ++s) {
        __syncthreads();
        if (t < NPTS * 2) {
            const float4* wrow = (const float4*)(offW + ((size_t)s * 72 + t) * HIDN);
            const float4* q4   = (const float4*)q_s;
            float a0 = 0.f;
            #pragma unroll 8
            for (int k = 0; k < HIDN / 4; ++k) {
                float4 w4 = wrow[k]; float4 qq = q4[k];
                a0 += w4.x * qq.x + w4.y * qq.y + w4.z * qq.z + w4.w * qq.w;
            }
            xy_s[t] = offB[s * 72 + t] + a0;
        }
        __syncthreads();
        if (t < NPTS) {
            float px = xy_s[2 * t + 0] + rpx;
            float py = xy_s[2 * t + 1] + rpy;
            float x = fminf(fmaxf(px * (float)WID - 0.5f, 0.f), (float)(WID - 1));
            float y = fminf(fmaxf(py * (float)HGT - 0.5f, 0.f), (float)(HGT - 1));
            float x0f = floorf(x), y0f = floorf(y);
            float wx = x - x0f, wy = y - y0f;
            int x0 = (int)x0f, y0 = (int)y0f;
            int x1 = min(x0 + 1, WID - 1), y1 = min(y0 + 1, HGT - 1);
            const float inv = 1.f / (float)NPTS;
            w_s[4 * t + 0] = (1.f - wx) * (1.f - wy) * inv;
            w_s[4 * t + 1] = wx * (1.f - wy) * inv;
            w_s[4 * t + 2] = (1.f - wx) * wy * inv;
            w_s[4 * t + 3] = wx * wy * inv;
            off_s[4 * t + 0] = y0 * WID + x0;
            off_s[4 * t + 1] = y0 * WID + x1;
            off_s[4 * t + 2] = y1 * WID + x0;
            off_s[4 * t + 3] = y1 * WID + x1;
        }
        __syncthreads();
        {
            float acc = 0.f;
            const float* basef = fm  + ((size_t)b * HIDN + t) * HW;
            const float* basep = pos + ((size_t)b * HIDN + t) * HW;
            #pragma unroll 6
            for (int p = 0; p < NPTS; ++p)
                for (int k = 0; k < 4; ++k) {
                    int idx = off_s[4 * p + k];
                    acc += w_s[4 * p + k] * (basef[idx] + basep[idx]);
                }
            fused_s[t] = acc;
        }
        __syncthreads();
        {
            const float4* w1 = (const float4*)(uW1 + ((size_t)s * HIDN + t) * (2 * HIDN));
            const float4* f4 = (const float4*)fused_s;
            const float4* q4 = (const float4*)q_s;
            float a0 = 0.f;
            #pragma unroll 8
            for (int k = 0; k < HIDN / 4; ++k) {
                float4 w4 = w1[k]; float4 c4 = f4[k];
                a0 += w4.x * c4.x + w4.y * c4.y + w4.z * c4.z + w4.w * c4.w;
            }
            #pragma unroll 8
            for (int k = 0; k < HIDN / 4; ++k) {
                float4 w4 = w1[HIDN / 4 + k]; float4 c4 = q4[k];
                a0 += w4.x * c4.x + w4.y * c4.y + w4.z * c4.z + w4.w * c4.w;
            }
            hdd_s[t] = fmaxf(uB1[s * HIDN + t] + a0, 0.f);
        }
        __syncthreads();
        {
            const float4* w2 = (const float4*)(uW2 + ((size_t)s * HIDN + t) * HIDN);
            const float4* h4 = (const float4*)hdd_s;
            float a0 = 0.f;
            #pragma unroll 8
            for (int k = 0; k < HIDN / 4; ++k) {
                float4 w4 = w2[k]; float4 c4 = h4[k];
                a0 += w4.x * c4.x + w4.y * c4.y + w4.z * c4.z + w4.w * c4.w;
            }
            q_s[t] = uB2[s * HIDN + t] + a0;
        }
    }
    __syncthreads();
    {
        const float4* w = (const float4*)(bW1 + (size_t)t * HIDN);
        const float4* q4 = (const float4*)q_s;
        float a0 = 0.f;
        #pragma unroll 8
        for (int k = 0; k < HIDN / 4; ++k) {
            float4 w4 = w[k]; float4 c4 = q4[k];
            a0 += w4.x * c4.x + w4.y * c4.y + w4.z * c4.z + w4.w * c4.w;
        }
        hdd_s[t] = fmaxf(bb1[t] + a0, 0.f);
    }
    __syncthreads();
    {
        const float4* w = (const float4*)(bW2 + (size_t)t * HIDN);
        const float4* h4 = (const float4*)hdd_s;
        float a0 = 0.f;
        #pragma unroll 8
        for (int k = 0; k < HIDN / 4; ++k) {
            float4 w4 = w[k]; float4 c4 = h4[k];
            a0 += w4.x * c4.x + w4.y * c4.y + w4.z * c4.z + w4.w * c4.w;
        }
        fused_s[t] = fmaxf(bb2[t] + a0, 0.f);
    }
    __syncthreads();
    if (t < 4) {
        const float* w = bW3 + (size_t)t * HIDN;
        float h = bb3[t];
        #pragma unroll 16
        for (int k = 0; k < HIDN; ++k) h += w[k] * fused_s[k];
        out[(size_t)b * 4 + t] = 1.f / (1.f + expf(-h));
    }
}

// ---------------------------------------------------------------------------
extern "C" void kernel_launch(void* const* d_in, const int* in_sizes, int n_in,
                              void* d_out, int out_size, void* d_ws, size_t ws_size,
                              hipStream_t stream)
{
    const float* q    = (const float*)d_in[0];
    const float* rp   = (const float*)d_in[1];
    const float* fm   = (const float*)d_in[2];
    const float* pos  = (const float*)d_in[3];
    const float* offW = (const float*)d_in[4];
    const float* offB = (const float*)d_in[5];
    const float* uW1  = (const float*)d_in[6];
    const float* uB1  = (const float*)d_in[7];
    const float* uW2  = (const float*)d_in[8];
    const float* uB2  = (const float*)d_in[9];
    const float* bW1  = (const float*)d_in[10];
    const float* bb1  = (const float*)d_in[11];
    const float* bW2  = (const float*)d_in[12];
    const float* bb2  = (const float*)d_in[13];
    const float* bW3  = (const float*)d_in[14];
    const float* bb3  = (const float*)d_in[15];
    float* out = (float*)d_out;

    const size_t need = (size_t)B_SZ * HW * HIDN * sizeof(unsigned short);
    if (ws_size >= need) {
        unsigned short* fmp = (unsigned short*)d_ws;
        prepass_kernel<128><<<dim3(3, 2, B_SZ), 512, 0, stream>>>(fm, pos, fmp, 0);
        prepass_kernel<16><<<dim3(1, 2, B_SZ), 512, 0, stream>>>(fm, pos, fmp, 384);
        mdetr4_kernel<<<B_SZ / MB, NTHR, 0, stream>>>(
            q, rp, fmp, offW, offB, uW1, uB1, uW2, uB2,
            bW1, bb1, bW2, bb2, bW3, bb3, out);
    } else {
        mdetr_direct_kernel<<<B_SZ, 256, 0, stream>>>(
            q, rp, fm, pos, offW, offB, uW1, uB1, uW2, uB2,
            bW1, bb1, bW2, bb2, bW3, bb3, out);
    }
}

// Round 7
// 351.803 us; speedup vs baseline: 1.0209x; 1.0209x over previous
//
#include <hip/hip_runtime.h>
#include <hip/hip_bf16.h>

#define B_SZ   1024
#define HIDN   256
#define NSTAGE 6
#define NPTS   36
#define HGT    20
#define WID    20
#define HW     400
#define MB     4
#define NTHR   1024

// f32 -> bf16 round-to-nearest-even
static __device__ __forceinline__ unsigned int f2bf(float x) {
    unsigned int u = __float_as_uint(x);
    u += 0x7FFFu + ((u >> 16) & 1u);
    return u >> 16;
}
// bf16 bits -> f32 (exact)
static __device__ __forceinline__ float bf2f(unsigned short h) {
    return __uint_as_float((unsigned int)h << 16);
}

// ---------------------------------------------------------------------------
// Prepass v6: fmp[b][hw][c] = bf16(fm[b][c][hw] + pos[b][c][hw]).
// Tile = ALL 400 hw x 64 channels. Channels are consecutive in memory, so
// each block reads ONE contiguous 102.4 KB region from fm and from pos
// (flat float4 sweep, 1KB per wave-instr) -> maximal DRAM page locality.
// LDS tile[64][404] ushort (51.7 KB, 8B-aligned rows, pad=4 to de-degenerate
// banks). Write phase: 2 channels/thread packed as uint -> 128B-contiguous
// full-L2-line stores. No tail kernel (whole hw range per block).
// 512 threads, 3 blocks/CU (LDS-limited) = 24 waves/CU.
// ---------------------------------------------------------------------------
__global__ __launch_bounds__(512) void prepass_kernel(
    const float* __restrict__ fm, const float* __restrict__ pos,
    unsigned short* __restrict__ fmp)
{
    const int b  = blockIdx.y;
    const int c0 = blockIdx.x * 64;
    __shared__ unsigned short tile[64 * 404];     // row stride 404 (808 B)
    const int t = threadIdx.x;

    // ---- read + convert phase: 64 rows x 400 f32 = 6400 float4, flat ----
    const size_t gbase = ((size_t)b * HIDN + c0) * HW;   // float offset, 16B-aligned
    for (int i = t; i < 6400; i += 512) {
        const int c  = i / 100;                   // local channel 0..63
        const int k4 = i - c * 100;               // float4 within row 0..99
        const float4 a = *(const float4*)(fm  + gbase + 4 * (size_t)i);
        const float4 p = *(const float4*)(pos + gbase + 4 * (size_t)i);
        uint2 pk;
        pk.x = f2bf(a.x + p.x) | (f2bf(a.y + p.y) << 16);
        pk.y = f2bf(a.z + p.z) | (f2bf(a.w + p.w) << 16);
        *(uint2*)&tile[c * 404 + 4 * k4] = pk;    // byte 808c+8k4 : 8B aligned
    }
    __syncthreads();

    // ---- transpose write phase: uint = 2 channels, 128B contiguous/32 lanes ----
    const int u2 = t & 31;                        // channel pair 0..31
    const int h0 = t >> 5;                        // 0..15
    uint* outp = (uint*)fmp;
    for (int hw = h0; hw < HW; hw += 16) {
        const unsigned int lo = tile[(2 * u2 + 0) * 404 + hw];
        const unsigned int hi = tile[(2 * u2 + 1) * 404 + hw];
        outp[(((size_t)b * HW + hw) * HIDN + c0) / 2 + u2] = lo | (hi << 16);
    }
}

// ---------------------------------------------------------------------------
// GEMM for 4 batch elements, no arrays (anti-spill), kp-split coalesced W.
// Thread layout: kp = t&7, og = t>>3 (0..127). O<=128 per pass.
// ACT: 0=none, 1=relu, 2=sigmoid.
// ---------------------------------------------------------------------------
template <int K, int O, int ACT>
__device__ __forceinline__ void gemm_v3(
    const float* __restrict__ W, const float* __restrict__ bias,
    const float* __restrict__ i0, const float* __restrict__ i1,
    const float* __restrict__ i2, const float* __restrict__ i3,
    float* __restrict__ o0, float* __restrict__ o1,
    float* __restrict__ o2, float* __restrict__ o3,
    int kp, int og)
{
    const float4* p0 = (const float4*)i0;
    const float4* p1 = (const float4*)i1;
    const float4* p2 = (const float4*)i2;
    const float4* p3 = (const float4*)i3;
    #pragma unroll
    for (int pass = 0; pass < (O + 127) / 128; ++pass) {
        const int o = pass * 128 + og;
        float a0 = 0.f, a1 = 0.f, a2 = 0.f, a3 = 0.f;
        if (o < O) {
            const float4* wr = (const float4*)(W + (size_t)o * K);
            #pragma unroll 4
            for (int jj = 0; jj < K / 32; ++jj) {
                const int j = kp + 8 * jj;
                const float4 w  = wr[j];
                const float4 v0 = p0[j];
                const float4 v1 = p1[j];
                const float4 v2 = p2[j];
                const float4 v3 = p3[j];
                a0 += w.x * v0.x + w.y * v0.y + w.z * v0.z + w.w * v0.w;
                a1 += w.x * v1.x + w.y * v1.y + w.z * v1.z + w.w * v1.w;
                a2 += w.x * v2.x + w.y * v2.y + w.z * v2.z + w.w * v2.w;
                a3 += w.x * v3.x + w.y * v3.y + w.z * v3.z + w.w * v3.w;
            }
        }
        a0 += __shfl_xor(a0, 1); a0 += __shfl_xor(a0, 2); a0 += __shfl_xor(a0, 4);
        a1 += __shfl_xor(a1, 1); a1 += __shfl_xor(a1, 2); a1 += __shfl_xor(a1, 4);
        a2 += __shfl_xor(a2, 1); a2 += __shfl_xor(a2, 2); a2 += __shfl_xor(a2, 4);
        a3 += __shfl_xor(a3, 1); a3 += __shfl_xor(a3, 2); a3 += __shfl_xor(a3, 4);
        if (kp == 0 && o < O) {
            const float bz = bias[o];
            float r0 = a0 + bz, r1 = a1 + bz, r2 = a2 + bz, r3 = a3 + bz;
            if (ACT == 1) {
                r0 = fmaxf(r0, 0.f); r1 = fmaxf(r1, 0.f);
                r2 = fmaxf(r2, 0.f); r3 = fmaxf(r3, 0.f);
            }
            if (ACT == 2) {
                r0 = 1.f / (1.f + expf(-r0)); r1 = 1.f / (1.f + expf(-r1));
                r2 = 1.f / (1.f + expf(-r2)); r3 = 1.f / (1.f + expf(-r3));
            }
            o0[o] = r0; o1[o] = r1; o2[o] = r2; o3[o] = r3;
        }
    }
}

// ---------------------------------------------------------------------------
// Fused main kernel v4: 1 block = 4 batch elements, 1024 threads, 256 blocks.
// Gathers from bf16 fmp (coalesced 128B/wave ushort loads).
// ---------------------------------------------------------------------------
__global__ __launch_bounds__(NTHR) void mdetr4_kernel(
    const float* __restrict__ q_in,  const float* __restrict__ refpt,
    const unsigned short* __restrict__ fmp,
    const float* __restrict__ offW,  const float* __restrict__ offB,
    const float* __restrict__ uW1,   const float* __restrict__ uB1,
    const float* __restrict__ uW2,   const float* __restrict__ uB2,
    const float* __restrict__ bW1,   const float* __restrict__ bb1,
    const float* __restrict__ bW2,   const float* __restrict__ bb2,
    const float* __restrict__ bW3,   const float* __restrict__ bb3,
    float* __restrict__ out)
{
    const int b0 = blockIdx.x * MB;
    const int t  = threadIdx.x;
    const int kp = t & 7;
    const int og = t >> 3;

    __shared__ __attribute__((aligned(16))) float cat_s[MB][2 * HIDN]; // [fused|q]
    __shared__ __attribute__((aligned(16))) float hdd_s[MB][HIDN];
    __shared__ __attribute__((aligned(16))) float xy_s[MB][80];
    __shared__ __attribute__((aligned(16))) float wgt_s[MB][144];
    __shared__ __attribute__((aligned(16))) int   off_s[MB][144];

    {   // initial q
        const int m = t >> 8, c = t & 255;
        cat_s[m][HIDN + c] = q_in[(size_t)(b0 + m) * HIDN + c];
    }

    for (int s = 0; s < NSTAGE; ++s) {
        __syncthreads();
        // ---- offset generator ----
        gemm_v3<HIDN, NPTS * 2, 0>(
            offW + (size_t)s * NPTS * 2 * HIDN, offB + s * NPTS * 2,
            cat_s[0] + HIDN, cat_s[1] + HIDN, cat_s[2] + HIDN, cat_s[3] + HIDN,
            xy_s[0], xy_s[1], xy_s[2], xy_s[3], kp, og);
        __syncthreads();
        // ---- tap prep ----
        if (t < MB * NPTS) {
            const int m = t / NPTS, p = t % NPTS;
            const int bm = b0 + m;
            float px = xy_s[m][2 * p + 0] + refpt[2 * bm + 0];
            float py = xy_s[m][2 * p + 1] + refpt[2 * bm + 1];
            float x = fminf(fmaxf(px * (float)WID - 0.5f, 0.f), (float)(WID - 1));
            float y = fminf(fmaxf(py * (float)HGT - 0.5f, 0.f), (float)(HGT - 1));
            float x0f = floorf(x), y0f = floorf(y);
            float wx = x - x0f,   wy = y - y0f;
            int x0 = (int)x0f, y0 = (int)y0f;
            int x1 = min(x0 + 1, WID - 1), y1 = min(y0 + 1, HGT - 1);
            const float inv = 1.f / (float)NPTS;
            wgt_s[m][4 * p + 0] = (1.f - wx) * (1.f - wy) * inv;
            wgt_s[m][4 * p + 1] = wx * (1.f - wy) * inv;
            wgt_s[m][4 * p + 2] = (1.f - wx) * wy * inv;
            wgt_s[m][4 * p + 3] = wx * wy * inv;
            off_s[m][4 * p + 0] = (y0 * WID + x0) * HIDN;
            off_s[m][4 * p + 1] = (y0 * WID + x1) * HIDN;
            off_s[m][4 * p + 2] = (y1 * WID + x0) * HIDN;
            off_s[m][4 * p + 3] = (y1 * WID + x1) * HIDN;
        }
        __syncthreads();
        // ---- gather + pooled mean -> fused ----
        {
            const int m = t >> 8, c = t & 255;
            const unsigned short* base = fmp + (size_t)(b0 + m) * HW * HIDN + c;
            float acc = 0.f;
            #pragma unroll 6
            for (int p = 0; p < NPTS; ++p) {
                const int4   o4 = ((const int4*)off_s[m])[p];
                const float4 w4 = ((const float4*)wgt_s[m])[p];
                acc += w4.x * bf2f(base[o4.x]) + w4.y * bf2f(base[o4.y])
                     + w4.z * bf2f(base[o4.z]) + w4.w * bf2f(base[o4.w]);
            }
            cat_s[m][c] = acc;
        }
        __syncthreads();
        // ---- MLP1 ----
        gemm_v3<2 * HIDN, HIDN, 1>(
            uW1 + (size_t)s * HIDN * 2 * HIDN, uB1 + s * HIDN,
            cat_s[0], cat_s[1], cat_s[2], cat_s[3],
            hdd_s[0], hdd_s[1], hdd_s[2], hdd_s[3], kp, og);
        __syncthreads();
        // ---- MLP2 ----
        gemm_v3<HIDN, HIDN, 0>(
            uW2 + (size_t)s * HIDN * HIDN, uB2 + s * HIDN,
            hdd_s[0], hdd_s[1], hdd_s[2], hdd_s[3],
            cat_s[0] + HIDN, cat_s[1] + HIDN, cat_s[2] + HIDN, cat_s[3] + HIDN,
            kp, og);
    }
    __syncthreads();
    // ---- bbox head ----
    gemm_v3<HIDN, HIDN, 1>(bW1, bb1,
        cat_s[0] + HIDN, cat_s[1] + HIDN, cat_s[2] + HIDN, cat_s[3] + HIDN,
        hdd_s[0], hdd_s[1], hdd_s[2], hdd_s[3], kp, og);
    __syncthreads();
    gemm_v3<HIDN, HIDN, 1>(bW2, bb2,
        hdd_s[0], hdd_s[1], hdd_s[2], hdd_s[3],
        cat_s[0], cat_s[1], cat_s[2], cat_s[3], kp, og);
    __syncthreads();
    gemm_v3<HIDN, 4, 2>(bW3, bb3,
        cat_s[0], cat_s[1], cat_s[2], cat_s[3],
        out + (size_t)(b0 + 0) * 4, out + (size_t)(b0 + 1) * 4,
        out + (size_t)(b0 + 2) * 4, out + (size_t)(b0 + 3) * 4, kp, og);
}

// ---------------------------------------------------------------------------
// Fallback (no workspace): 1 block = 1 batch element, direct strided gather.
// ---------------------------------------------------------------------------
__global__ __launch_bounds__(256) void mdetr_direct_kernel(
    const float* __restrict__ q_in,  const float* __restrict__ refpt,
    const float* __restrict__ fm,    const float* __restrict__ pos,
    const float* __restrict__ offW,  const float* __restrict__ offB,
    const float* __restrict__ uW1,   const float* __restrict__ uB1,
    const float* __restrict__ uW2,   const float* __restrict__ uB2,
    const float* __restrict__ bW1,   const float* __restrict__ bb1,
    const float* __restrict__ bW2,   const float* __restrict__ bb2,
    const float* __restrict__ bW3,   const float* __restrict__ bb3,
    float* __restrict__ out)
{
    const int b = blockIdx.x;
    const int t = threadIdx.x;
    __shared__ __attribute__((aligned(16))) float q_s[HIDN];
    __shared__ __attribute__((aligned(16))) float fused_s[HIDN];
    __shared__ __attribute__((aligned(16))) float hdd_s[HIDN];
    __shared__ float xy_s[NPTS * 2];
    __shared__ int   off_s[NPTS * 4];
    __shared__ float w_s[NPTS * 4];

    q_s[t] = q_in[(size_t)b * HIDN + t];
    const float rpx = refpt[2 * b + 0];
    const float rpy = refpt[2 * b + 1];

    for (int s = 0; s < NSTAGE; ++s) {
        __syncthreads();
        if (t < NPTS * 2) {
            const float4* wrow = (const float4*)(offW + ((size_t)s * 72 + t) * HIDN);
            const float4* q4   = (const float4*)q_s;
            float a0 = 0.f;
            #pragma unroll 8
            for (int k = 0; k < HIDN / 4; ++k) {
                float4 w4 = wrow[k]; float4 qq = q4[k];
                a0 += w4.x * qq.x + w4.y * qq.y + w4.z * qq.z + w4.w * qq.w;
            }
            xy_s[t] = offB[s * 72 + t] + a0;
        }
        __syncthreads();
        if (t < NPTS) {
            float px = xy_s[2 * t + 0] + rpx;
            float py = xy_s[2 * t + 1] + rpy;
            float x = fminf(fmaxf(px * (float)WID - 0.5f, 0.f), (float)(WID - 1));
            float y = fminf(fmaxf(py * (float)HGT - 0.5f, 0.f), (float)(HGT - 1));
            float x0f = floorf(x), y0f = floorf(y);
            float wx = x - x0f, wy = y - y0f;
            int x0 = (int)x0f, y0 = (int)y0f;
            int x1 = min(x0 + 1, WID - 1), y1 = min(y0 + 1, HGT - 1);
            const float inv = 1.f / (float)NPTS;
            w_s[4 * t + 0] = (1.f - wx) * (1.f - wy) * inv;
            w_s[4 * t + 1] = wx * (1.f - wy) * inv;
            w_s[4 * t + 2] = (1.f - wx) * wy * inv;
            w_s[4 * t + 3] = wx * wy * inv;
            off_s[4 * t + 0] = y0 * WID + x0;
            off_s[4 * t + 1] = y0 * WID + x1;
            off_s[4 * t + 2] = y1 * WID + x0;
            off_s[4 * t + 3] = y1 * WID + x1;
        }
        __syncthreads();
        {
            float acc = 0.f;
            const float* basef = fm  + ((size_t)b * HIDN + t) * HW;
            const float* basep = pos + ((size_t)b * HIDN + t) * HW;
            #pragma unroll 6
            for (int p = 0; p < NPTS; ++p)
                for (int k = 0; k < 4; ++k) {
                    int idx = off_s[4 * p + k];
                    acc += w_s[4 * p + k] * (basef[idx] + basep[idx]);
                }
            fused_s[t] = acc;
        }
        __syncthreads();
        {
            const float4* w1 = (const float4*)(uW1 + ((size_t)s * HIDN + t) * (2 * HIDN));
            const float4* f4 = (const float4*)fused_s;
            const float4* q4 = (const float4*)q_s;
            float a0 = 0.f;
            #pragma unroll 8
            for (int k = 0; k < HIDN / 4; ++k) {
                float4 w4 = w1[k]; float4 c4 = f4[k];
                a0 += w4.x * c4.x + w4.y * c4.y + w4.z * c4.z + w4.w * c4.w;
            }
            #pragma unroll 8
            for (int k = 0; k < HIDN / 4; ++k) {
                float4 w4 = w1[HIDN / 4 + k]; float4 c4 = q4[k];
                a0 += w4.x * c4.x + w4.y * c4.y + w4.z * c4.z + w4.w * c4.w;
            }
            hdd_s[t] = fmaxf(uB1[s * HIDN + t] + a0, 0.f);
        }
        __syncthreads();
        {
            const float4* w2 = (const float4*)(uW2 + ((size_t)s * HIDN + t) * HIDN);
            const float4* h4 = (const float4*)hdd_s;
            float a0 = 0.f;
            #pragma unroll 8
            for (int k = 0; k < HIDN / 4; ++k) {
                float4 w4 = w2[k]; float4 c4 = h4[k];
                a0 += w4.x * c4.x + w4.y * c4.y + w4.z * c4.z + w4.w * c4.w;
            }
            q_s[t] = uB2[s * HIDN + t] + a0;
        }
    }
    __syncthreads();
    {
        const float4* w = (const float4*)(bW1 + (size_t)t * HIDN);
        const float4* q4 = (const float4*)q_s;
        float a0 = 0.f;
        #pragma unroll 8
        for (int k = 0; k < HIDN / 4; ++k) {
            float4 w4 = w[k]; float4 c4 = q4[k];
            a0 += w4.x * c4.x + w4.y * c4.y + w4.z * c4.z + w4.w * c4.w;
        }
        hdd_s[t] = fmaxf(bb1[t] + a0, 0.f);
    }
    __syncthreads();
    {
        const float4* w = (const float4*)(bW2 + (size_t)t * HIDN);
        const float4* h4 = (const float4*)hdd_s;
        float a0 = 0.f;
        #pragma unroll 8
        for (int k = 0; k < HIDN / 4; ++k) {
            float4 w4 = w[k]; float4 c4 = h4[k];
            a0 += w4.x * c4.x + w4.y * c4.y + w4.z * c4.z + w4.w * c4.w;
        }
        fused_s[t] = fmaxf(bb2[t] + a0, 0.f);
    }
    __syncthreads();
    if (t < 4) {
        const float* w = bW3 + (size_t)t * HIDN;
        float h = bb3[t];
        #pragma unroll 16
        for (int k = 0; k < HIDN; ++k) h += w[k] * fused_s[k];
        out[(size_t)b * 4 + t] = 1.f / (1.f + expf(-h));
    }
}

// ---------------------------------------------------------------------------
extern "C" void kernel_launch(void* const* d_in, const int* in_sizes, int n_in,
                              void* d_out, int out_size, void* d_ws, size_t ws_size,
                              hipStream_t stream)
{
    const float* q    = (const float*)d_in[0];
    const float* rp   = (const float*)d_in[1];
    const float* fm   = (const float*)d_in[2];
    const float* pos  = (const float*)d_in[3];
    const float* offW = (const float*)d_in[4];
    const float* offB = (const float*)d_in[5];
    const float* uW1  = (const float*)d_in[6];
    const float* uB1  = (const float*)d_in[7];
    const float* uW2  = (const float*)d_in[8];
    const float* uB2  = (const float*)d_in[9];
    const float* bW1  = (const float*)d_in[10];
    const float* bb1  = (const float*)d_in[11];
    const float* bW2  = (const float*)d_in[12];
    const float* bb2  = (const float*)d_in[13];
    const float* bW3  = (const float*)d_in[14];
    const float* bb3  = (const float*)d_in[15];
    float* out = (float*)d_out;

    const size_t need = (size_t)B_SZ * HW * HIDN * sizeof(unsigned short);
    if (ws_size >= need) {
        unsigned short* fmp = (unsigned short*)d_ws;
        prepass_kernel<<<dim3(HIDN / 64, B_SZ), 512, 0, stream>>>(fm, pos, fmp);
        mdetr4_kernel<<<B_SZ / MB, NTHR, 0, stream>>>(
            q, rp, fmp, offW, offB, uW1, uB1, uW2, uB2,
            bW1, bb1, bW2, bb2, bW3, bb3, out);
    } else {
        mdetr_direct_kernel<<<B_SZ, 256, 0, stream>>>(
            q, rp, fm, pos, offW, offB, uW1, uB1, uW2, uB2,
            bW1, bb1, bW2, bb2, bW3, bb3, out);
    }
}